// Round 1
// baseline (382.885 us; speedup 1.0000x reference)
//
#include <hip/hip_runtime.h>

#define C_DIM 1024
#define N_DIM 1024
#define O_DIM 2048
#define K_NN  20

// ---------------------------------------------------------------------------
// Kernel 1: column squared-norm partials, fp64 accumulation (deterministic).
// grid (4 j-blocks, 8 c-blocks) x 256 threads. part[cb][j] = sum over 128 c.
// ---------------------------------------------------------------------------
__global__ __launch_bounds__(256) void norms_partial_kernel(
    const float* __restrict__ x, double* __restrict__ part) {
  int j = blockIdx.x * 256 + threadIdx.x;
  int cb = blockIdx.y;
  double acc = 0.0;
  int c0 = cb * 128;
#pragma unroll 8
  for (int c = c0; c < c0 + 128; ++c) {
    float v = x[(size_t)c * N_DIM + j];
    acc = fma((double)v, (double)v, acc);
  }
  part[(size_t)cb * N_DIM + j] = acc;
}

__global__ __launch_bounds__(256) void norms_reduce_kernel(
    const double* __restrict__ part, double* __restrict__ s_d) {
  int j = blockIdx.x * 256 + threadIdx.x;
  double a = 0.0;
#pragma unroll
  for (int cb = 0; cb < 8; ++cb) a += part[(size_t)cb * N_DIM + j];
  s_d[j] = a;
}

// ---------------------------------------------------------------------------
// K-major fp32 GEMM: C[M x N] = A^T * B where A is (Kd x M), B is (Kd x N),
// both K-major (row = k, contiguous in M/N). BM=128, BN=64, BK=16,
// 256 threads, 8x4 micro-tile (m split 2x4 to keep LDS reads <=2-way).
// ---------------------------------------------------------------------------
template <int BM, int BN, int BK>
__global__ __launch_bounds__(256) void gemm_kk(
    const float* __restrict__ A, const float* __restrict__ B,
    float* __restrict__ Cm, int M, int N, int Kd) {
  __shared__ float Alds[BK][BM];
  __shared__ float Blds[BK][BN];
  int t = threadIdx.x;
  int tx = t & 15;   // n-dim: 4 cols
  int ty = t >> 4;   // m-dim: 2x4 rows
  int m0 = blockIdx.y * BM;
  int n0 = blockIdx.x * BN;
  float acc[8][4] = {};

  for (int k0 = 0; k0 < Kd; k0 += BK) {
    // stage tiles through registers
    float4 a_s[2], b_s;
#pragma unroll
    for (int r = 0; r < 2; ++r) {
      int id = t + r * 256;          // 512 float4 in A tile
      int kk = id >> 5, mc = id & 31;
      a_s[r] = *(const float4*)&A[(size_t)(k0 + kk) * M + m0 + mc * 4];
    }
    {
      int kk = t >> 4, nc = t & 15;  // 256 float4 in B tile
      b_s = *(const float4*)&B[(size_t)(k0 + kk) * N + n0 + nc * 4];
    }
    __syncthreads();  // previous compute done before overwriting LDS
#pragma unroll
    for (int r = 0; r < 2; ++r) {
      int id = t + r * 256;
      int kk = id >> 5, mc = id & 31;
      *(float4*)&Alds[kk][mc * 4] = a_s[r];
    }
    {
      int kk = t >> 4, nc = t & 15;
      *(float4*)&Blds[kk][nc * 4] = b_s;
    }
    __syncthreads();
#pragma unroll
    for (int kk = 0; kk < BK; ++kk) {
      float4 a0 = *(const float4*)&Alds[kk][ty * 4];
      float4 a1 = *(const float4*)&Alds[kk][64 + ty * 4];
      float4 b0 = *(const float4*)&Blds[kk][tx * 4];
      float am[8] = {a0.x, a0.y, a0.z, a0.w, a1.x, a1.y, a1.z, a1.w};
      float bn[4] = {b0.x, b0.y, b0.z, b0.w};
#pragma unroll
      for (int i = 0; i < 8; ++i)
#pragma unroll
        for (int jj = 0; jj < 4; ++jj)
          acc[i][jj] = fmaf(am[i], bn[jj], acc[i][jj]);
    }
  }
#pragma unroll
  for (int i = 0; i < 8; ++i) {
    int row = m0 + ((i < 4) ? (ty * 4 + i) : (64 + ty * 4 + (i - 4)));
    float4 v = make_float4(acc[i][0], acc[i][1], acc[i][2], acc[i][3]);
    *(float4*)&Cm[(size_t)row * N + n0 + tx * 4] = v;
  }
}

// ---------------------------------------------------------------------------
// Top-20 per row of d_j = 2*dot[i][j] - s_d[j]  (s_i dropped: row-constant).
// One wave per row; values held in registers (16 doubles/lane); 20 rounds of
// wave argmax with tie -> lowest index (matches jax.lax.top_k).
// ---------------------------------------------------------------------------
__global__ __launch_bounds__(64) void topk_kernel(
    const float* __restrict__ dotf, const double* __restrict__ s_d,
    int* __restrict__ idxo) {
  int i = blockIdx.x;
  int l = threadIdx.x;
  double d[16];
#pragma unroll
  for (int q = 0; q < 16; ++q) {
    int j = q * 64 + l;
    d[q] = 2.0 * (double)dotf[(size_t)i * N_DIM + j] - s_d[j];
  }
  for (int r = 0; r < K_NN; ++r) {
    double bv = -1e300;
    int bj = N_DIM;
#pragma unroll
    for (int q = 0; q < 16; ++q) {
      int j = q * 64 + l;
      if (d[q] > bv) { bv = d[q]; bj = j; }  // strict > : lower q wins ties
    }
#pragma unroll
    for (int off = 32; off; off >>= 1) {
      double ov = __shfl_xor(bv, off);
      int oj = __shfl_xor(bj, off);
      if (ov > bv || (ov == bv && oj < bj)) { bv = ov; bj = oj; }
    }
    if (l == 0) idxo[i * K_NN + r] = bj;
    int kq = bj >> 6, kl = bj & 63;
    if (l == kl) {
#pragma unroll
      for (int q = 0; q < 16; ++q)
        if (q == kq) d[q] = -1e300;  // static index, no scratch
    }
  }
}

// ---------------------------------------------------------------------------
// Tiled transpose: src (R x C) -> dst (C x R). Dims multiples of 32.
// ---------------------------------------------------------------------------
__global__ __launch_bounds__(256) void transpose_kernel(
    const float* __restrict__ src, float* __restrict__ dst, int R, int C) {
  __shared__ float tile[32][33];
  int bx = blockIdx.x * 32;  // col of src
  int by = blockIdx.y * 32;  // row of src
  int tx = threadIdx.x & 31;
  int ty = threadIdx.x >> 5;  // 0..7
#pragma unroll
  for (int r = 0; r < 4; ++r)
    tile[ty + 8 * r][tx] = src[(size_t)(by + ty + 8 * r) * C + bx + tx];
  __syncthreads();
#pragma unroll
  for (int r = 0; r < 4; ++r)
    dst[(size_t)(bx + ty + 8 * r) * R + by + tx] = tile[tx][ty + 8 * r];
}

// ---------------------------------------------------------------------------
// Gather + eps-residual: hT[n][c] = (1+epsT[n][c])*xT[n][c] + sum_k xT[idx][c]
// ---------------------------------------------------------------------------
__global__ __launch_bounds__(256) void gather_kernel(
    const float* __restrict__ xT, const float* __restrict__ epsT,
    const int* __restrict__ idxo, float* __restrict__ hT) {
  int n = blockIdx.x;
  int c0 = threadIdx.x * 4;
  float4 xv = *(const float4*)&xT[(size_t)n * C_DIM + c0];
  float4 ev = *(const float4*)&epsT[(size_t)n * C_DIM + c0];
  float ax = (1.f + ev.x) * xv.x;
  float ay = (1.f + ev.y) * xv.y;
  float az = (1.f + ev.z) * xv.z;
  float aw = (1.f + ev.w) * xv.w;
#pragma unroll
  for (int k = 0; k < K_NN; ++k) {
    int j = idxo[n * K_NN + k];  // uniform per block -> broadcast
    float4 nv = *(const float4*)&xT[(size_t)j * C_DIM + c0];
    ax += nv.x; ay += nv.y; az += nv.z; aw += nv.w;
  }
  float4 o = make_float4(ax, ay, az, aw);
  *(float4*)&hT[(size_t)n * C_DIM + c0] = o;
}

// ---------------------------------------------------------------------------
// Launch
// ---------------------------------------------------------------------------
extern "C" void kernel_launch(void* const* d_in, const int* in_sizes, int n_in,
                              void* d_out, int out_size, void* d_ws,
                              size_t ws_size, hipStream_t stream) {
  const float* x = (const float*)d_in[0];    // (C, N)
  const float* W = (const float*)d_in[1];    // (O, C, 1, 1)
  const float* eps = (const float*)d_in[2];  // (C, N, 1)
  float* out = (float*)d_out;                // (O, N)
  char* ws = (char*)d_ws;

  double* part = (double*)(ws + 0);          //  64 KB
  double* s_d  = (double*)(ws + 65536);      //   8 KB
  float* dotf  = (float*)(ws + 73728);       //   4 MB
  int* idxo    = (int*)(ws + 4268032);       //  80 KB
  float* xT    = (float*)(ws + 4349952);     //   4 MB  (N x C)
  float* epsT  = (float*)(ws + 8544256);     //   4 MB  (N x C)
  float* WT    = (float*)(ws + 12738560);    //   8 MB  (C x O)
  float* hT    = (float*)(ws + 21127168);    //   4 MB  (N x C)
  float* hC    = (float*)(ws + 25321472);    //   4 MB  (C x N)

  // squared norms (fp64, deterministic)
  norms_partial_kernel<<<dim3(4, 8), 256, 0, stream>>>(x, part);
  norms_reduce_kernel<<<4, 256, 0, stream>>>(part, s_d);

  // dot = x^T x  (K-major GEMM, A=B=x)
  gemm_kk<128, 64, 16><<<dim3(16, 8), 256, 0, stream>>>(
      x, x, dotf, N_DIM, N_DIM, C_DIM);

  // top-20 neighbor indices per row
  topk_kernel<<<N_DIM, 64, 0, stream>>>(dotf, s_d, idxo);

  // transposes for coalesced gather / K-major final GEMM
  transpose_kernel<<<dim3(32, 32), 256, 0, stream>>>(x, xT, C_DIM, N_DIM);
  transpose_kernel<<<dim3(32, 32), 256, 0, stream>>>(eps, epsT, C_DIM, N_DIM);
  transpose_kernel<<<dim3(32, 64), 256, 0, stream>>>(W, WT, O_DIM, C_DIM);

  // h^T = (1+eps^T) .* x^T + neighbor sums
  gather_kernel<<<N_DIM, 256, 0, stream>>>(xT, epsT, idxo, hT);

  // back to K-major for the output GEMM
  transpose_kernel<<<dim3(32, 32), 256, 0, stream>>>(hT, hC, N_DIM, C_DIM);

  // out = W @ h   (A = WT: K x O, B = hC: K x N)
  gemm_kk<128, 64, 16><<<dim3(16, 16), 256, 0, stream>>>(
      WT, hC, out, O_DIM, N_DIM, C_DIM);
}

// Round 2
// 187.327 us; speedup vs baseline: 2.0439x; 2.0439x over previous
//
#include <hip/hip_runtime.h>

#define C_DIM 1024
#define N_DIM 1024
#define O_DIM 2048
#define K_NN  20
#define KCAT  3072  // 3 * 1024 (hi*hi + hi*lo + lo*hi split-bf16 GEMM)

typedef __attribute__((ext_vector_type(8))) short bf16x8;
typedef __attribute__((ext_vector_type(4))) float f32x4;

__device__ __forceinline__ unsigned short f2bf(float f) {
  unsigned u = __float_as_uint(f);
  unsigned r = (u + 0x7fffu + ((u >> 16) & 1u)) >> 16;  // RNE
  return (unsigned short)r;
}
__device__ __forceinline__ float bf2f(unsigned short h) {
  return __uint_as_float((unsigned)h << 16);
}

// async global->LDS, 16B per lane, linear dest (wave base + lane*16)
#define GLOAD16(gp, lp)                                                     \
  __builtin_amdgcn_global_load_lds(                                         \
      (const __attribute__((address_space(1))) unsigned int*)(uintptr_t)(gp), \
      (__attribute__((address_space(3))) unsigned int*)(uintptr_t)(lp), 16, \
      0, 0)

// ---------------------------------------------------------------------------
// Column squared-norms, fp64 (deterministic, feeds top-k margins).
// ---------------------------------------------------------------------------
__global__ __launch_bounds__(256) void norms_partial_kernel(
    const float* __restrict__ x, double* __restrict__ part) {
  int j = blockIdx.x * 256 + threadIdx.x;
  int cb = blockIdx.y;
  double acc = 0.0;
  int c0 = cb * 128;
#pragma unroll 8
  for (int c = c0; c < c0 + 128; ++c) {
    float v = x[(size_t)c * N_DIM + j];
    acc = fma((double)v, (double)v, acc);
  }
  part[(size_t)cb * N_DIM + j] = acc;
}

__global__ __launch_bounds__(256) void norms_reduce_kernel(
    const double* __restrict__ part, double* __restrict__ s_d) {
  int j = blockIdx.x * 256 + threadIdx.x;
  double a = 0.0;
#pragma unroll
  for (int cb = 0; cb < 8; ++cb) a += part[(size_t)cb * N_DIM + j];
  s_d[j] = a;
}

// ---------------------------------------------------------------------------
// fp32 K-major GEMM, 64x64 tile, split-K (grid.z), partials out.
// A (Kd x M), B (Kd x N) K-major. 256 thr, 4x4 micro-tile.
// ---------------------------------------------------------------------------
template <int KZ>
__global__ __launch_bounds__(256) void gemm64_split(
    const float* __restrict__ A, const float* __restrict__ B,
    float* __restrict__ P, int M, int N) {
  __shared__ float Al[16][64];
  __shared__ float Bl[16][64];
  int t = threadIdx.x;
  int tx = t & 15, ty = t >> 4;
  int m0 = blockIdx.y * 64, n0 = blockIdx.x * 64;
  int z = blockIdx.z;
  int kk = t >> 4, c4 = (t & 15) * 4;
  float acc[4][4] = {};
  for (int k0 = z * KZ; k0 < (z + 1) * KZ; k0 += 16) {
    float4 av = *(const float4*)&A[(size_t)(k0 + kk) * M + m0 + c4];
    float4 bv = *(const float4*)&B[(size_t)(k0 + kk) * N + n0 + c4];
    __syncthreads();
    *(float4*)&Al[kk][c4] = av;
    *(float4*)&Bl[kk][c4] = bv;
    __syncthreads();
#pragma unroll
    for (int q = 0; q < 16; ++q) {
      float4 a = *(const float4*)&Al[q][ty * 4];
      float4 b = *(const float4*)&Bl[q][tx * 4];
      float am[4] = {a.x, a.y, a.z, a.w};
      float bn[4] = {b.x, b.y, b.z, b.w};
#pragma unroll
      for (int i = 0; i < 4; ++i)
#pragma unroll
        for (int j = 0; j < 4; ++j)
          acc[i][j] = fmaf(am[i], bn[j], acc[i][j]);
    }
  }
#pragma unroll
  for (int i = 0; i < 4; ++i) {
    float4 v = make_float4(acc[i][0], acc[i][1], acc[i][2], acc[i][3]);
    *(float4*)&P[((size_t)z * M + m0 + ty * 4 + i) * N + n0 + tx * 4] = v;
  }
}

// ---------------------------------------------------------------------------
// Top-20 of d_j = 2*sum_z P[z][i][j] - s_d[j]; fp64 combine; tie -> low idx.
// ---------------------------------------------------------------------------
__global__ __launch_bounds__(64) void topk_kernel(
    const float* __restrict__ P, const double* __restrict__ s_d,
    int* __restrict__ idxo) {
  int i = blockIdx.x;
  int l = threadIdx.x;
  double d[16];
#pragma unroll
  for (int q = 0; q < 16; ++q) {
    int j = q * 64 + l;
    double s = 0.0;
#pragma unroll
    for (int z = 0; z < 4; ++z)
      s += (double)P[((size_t)z * N_DIM + i) * N_DIM + j];
    d[q] = 2.0 * s - s_d[j];
  }
  for (int r = 0; r < K_NN; ++r) {
    double bv = -1e300;
    int bj = N_DIM;
#pragma unroll
    for (int q = 0; q < 16; ++q) {
      int j = q * 64 + l;
      if (d[q] > bv) { bv = d[q]; bj = j; }
    }
#pragma unroll
    for (int off = 32; off; off >>= 1) {
      double ov = __shfl_xor(bv, off);
      int oj = __shfl_xor(bj, off);
      if (ov > bv || (ov == bv && oj < bj)) { bv = ov; bj = oj; }
    }
    if (l == 0) idxo[i * K_NN + r] = bj;
    int kq = bj >> 6, kl = bj & 63;
    if (l == kl) {
#pragma unroll
      for (int q = 0; q < 16; ++q)
        if (q == kq) d[q] = -1e300;
    }
  }
}

// ---------------------------------------------------------------------------
// Tiled fp32 transpose (R x C) -> (C x R), dims multiples of 32.
// ---------------------------------------------------------------------------
__global__ __launch_bounds__(256) void transpose_kernel(
    const float* __restrict__ src, float* __restrict__ dst, int R, int C) {
  __shared__ float tile[32][33];
  int bx = blockIdx.x * 32;
  int by = blockIdx.y * 32;
  int tx = threadIdx.x & 31;
  int ty = threadIdx.x >> 5;
#pragma unroll
  for (int r = 0; r < 4; ++r)
    tile[ty + 8 * r][tx] = src[(size_t)(by + ty + 8 * r) * C + bx + tx];
  __syncthreads();
#pragma unroll
  for (int r = 0; r < 4; ++r)
    dst[(size_t)(bx + ty + 8 * r) * R + by + tx] = tile[tx][ty + 8 * r];
}

// ---------------------------------------------------------------------------
// Gather + eps residual: hT[n][c] = (1+epsT[n][c])*xT[n][c] + sum_k xT[idx][c]
// ---------------------------------------------------------------------------
__global__ __launch_bounds__(256) void gather_kernel(
    const float* __restrict__ xT, const float* __restrict__ epsT,
    const int* __restrict__ idxo, float* __restrict__ hT) {
  int n = blockIdx.x;
  int c0 = threadIdx.x * 4;
  float4 xv = *(const float4*)&xT[(size_t)n * C_DIM + c0];
  float4 ev = *(const float4*)&epsT[(size_t)n * C_DIM + c0];
  float ax = (1.f + ev.x) * xv.x;
  float ay = (1.f + ev.y) * xv.y;
  float az = (1.f + ev.z) * xv.z;
  float aw = (1.f + ev.w) * xv.w;
#pragma unroll
  for (int k = 0; k < K_NN; ++k) {
    int j = idxo[n * K_NN + k];
    float4 nv = *(const float4*)&xT[(size_t)j * C_DIM + c0];
    ax += nv.x; ay += nv.y; az += nv.z; aw += nv.w;
  }
  *(float4*)&hT[(size_t)n * C_DIM + c0] = make_float4(ax, ay, az, aw);
}

// ---------------------------------------------------------------------------
// fp32 -> concatenated split-bf16 operand, MFMA-fragment-permuted + XOR
// chunk-swizzled per 64B window.
//   dst row m, k' = seg*1024 + g*32 + ...; window = 64B = 4 chunks of 16B.
//   physical chunk c holds logical chunk cl = c ^ s(m),
//   s(m) = (m&3)^((m>>2)&3). Logical chunk h holds k = 32g + 4h+{0..3},
//   then 32g + 16 + 4h+{0..3}  (mfma_16x16x32_bf16 A/B lane layout).
//   pattern 0 (A side): segs = hi, hi, lo.  pattern 1 (B side): hi, lo, hi.
// ---------------------------------------------------------------------------
__global__ __launch_bounds__(256) void conv_cat_kernel(
    const float* __restrict__ src, unsigned short* __restrict__ dst,
    int pattern) {
  int id = blockIdx.x * 256 + threadIdx.x;  // one 16B output chunk
  int c = id & 3;
  int wih = (id >> 2) % 96;
  int m = id / 384;
  int seg = wih >> 5, g = wih & 31;
  int s = (m & 3) ^ ((m >> 2) & 3);
  int cl = c ^ s;
  int kb = g * 32 + 4 * cl;
  const float* p = src + (size_t)m * 1024 + kb;
  float4 v0 = *(const float4*)p;         // k = kb .. kb+3
  float4 v1 = *(const float4*)(p + 16);  // k = kb+16 .. kb+19
  bool lo = (pattern == 0) ? (seg == 2) : (seg == 1);
  float vv[8] = {v0.x, v0.y, v0.z, v0.w, v1.x, v1.y, v1.z, v1.w};
  unsigned o[8];
#pragma unroll
  for (int i = 0; i < 8; ++i) {
    unsigned short hb = f2bf(vv[i]);
    if (lo) {
      float r = vv[i] - bf2f(hb);
      o[i] = f2bf(r);
    } else {
      o[i] = hb;
    }
  }
  uint4 pack;
  pack.x = o[0] | (o[1] << 16);
  pack.y = o[2] | (o[3] << 16);
  pack.z = o[4] | (o[5] << 16);
  pack.w = o[6] | (o[7] << 16);
  *(uint4*)(dst + (size_t)m * KCAT + seg * 1024 + g * 32 + c * 8) = pack;
}

// ---------------------------------------------------------------------------
// bf16 MFMA GEMM: out[M x N] = Acat x Bcat^T over K'=3072.
// Acat (M x K'), Bcat (N x K'), both fragment-permuted + swizzled (above).
// 64x64 tile, 256 thr = 4 waves (2x2), wave = 32x32 = 2x2 mfma frags.
// global_load_lds staging (16B/lane), m97-style 2-barrier loop.
// ---------------------------------------------------------------------------
__global__ __launch_bounds__(256) void mfma_gemm(
    const unsigned short* __restrict__ Acat,
    const unsigned short* __restrict__ Bcat, float* __restrict__ out, int M,
    int N) {
  __shared__ unsigned short Alds[64 * 32];  // [m][32k], 64B rows, 4 KB
  __shared__ unsigned short Blds[64 * 32];
  int t = threadIdx.x;
  int w = t >> 6, l = t & 63;
  int m0 = blockIdx.y * 64, n0 = blockIdx.x * 64;
  int wr = w >> 1, wc = w & 1;
  int h = (l >> 4) & 3, c16 = l & 15;
  int sw = (c16 & 3) ^ ((c16 >> 2) & 3);  // == s(row) for row = 16a + c16
  int hc = ((h ^ sw) * 8);                // ushort offset of lane's chunk
  f32x4 acc00 = {}, acc01 = {}, acc10 = {}, acc11 = {};
  int srow = t >> 2, sc = t & 3;
  const char* gA = (const char*)(Acat + (size_t)(m0 + srow) * KCAT) + sc * 16;
  const char* gB = (const char*)(Bcat + (size_t)(n0 + srow) * KCAT) + sc * 16;
  char* lA = (char*)Alds + t * 16;
  char* lB = (char*)Blds + t * 16;
  const unsigned short* a0p = Alds + (wr * 32 + 0 + c16) * 32 + hc;
  const unsigned short* a1p = Alds + (wr * 32 + 16 + c16) * 32 + hc;
  const unsigned short* b0p = Blds + (wc * 32 + 0 + c16) * 32 + hc;
  const unsigned short* b1p = Blds + (wc * 32 + 16 + c16) * 32 + hc;
  for (int g = 0; g < KCAT / 32; ++g) {
    GLOAD16(gA + g * 64, lA);
    GLOAD16(gB + g * 64, lB);
    __syncthreads();  // drain vmcnt + barrier: tile ready
    bf16x8 a0 = *(const bf16x8*)a0p;
    bf16x8 a1 = *(const bf16x8*)a1p;
    bf16x8 b0 = *(const bf16x8*)b0p;
    bf16x8 b1 = *(const bf16x8*)b1p;
    acc00 = __builtin_amdgcn_mfma_f32_16x16x32_bf16(a0, b0, acc00, 0, 0, 0);
    acc01 = __builtin_amdgcn_mfma_f32_16x16x32_bf16(a0, b1, acc01, 0, 0, 0);
    acc10 = __builtin_amdgcn_mfma_f32_16x16x32_bf16(a1, b0, acc10, 0, 0, 0);
    acc11 = __builtin_amdgcn_mfma_f32_16x16x32_bf16(a1, b1, acc11, 0, 0, 0);
    __syncthreads();  // compute done before next stage overwrites
  }
  // C/D: col = lane&15, row = (lane>>4)*4 + reg
#define STORE_FRAG(av, mi, ni)                                       \
  {                                                                  \
    int rb = m0 + wr * 32 + (mi) * 16 + h * 4;                       \
    int col = n0 + wc * 32 + (ni) * 16 + c16;                        \
    out[(size_t)(rb + 0) * N + col] = av[0];                         \
    out[(size_t)(rb + 1) * N + col] = av[1];                         \
    out[(size_t)(rb + 2) * N + col] = av[2];                         \
    out[(size_t)(rb + 3) * N + col] = av[3];                         \
  }
  STORE_FRAG(acc00, 0, 0)
  STORE_FRAG(acc01, 0, 1)
  STORE_FRAG(acc10, 1, 0)
  STORE_FRAG(acc11, 1, 1)
#undef STORE_FRAG
}

// ---------------------------------------------------------------------------
// Launch
// ---------------------------------------------------------------------------
extern "C" void kernel_launch(void* const* d_in, const int* in_sizes, int n_in,
                              void* d_out, int out_size, void* d_ws,
                              size_t ws_size, hipStream_t stream) {
  const float* x = (const float*)d_in[0];    // (C, N) K-major for dist
  const float* W = (const float*)d_in[1];    // (O, C) M-major for out GEMM
  const float* eps = (const float*)d_in[2];  // (C, N)
  float* out = (float*)d_out;                // (O, N)
  char* ws = (char*)d_ws;

  double* part = (double*)(ws + 0);              //  64 KB
  double* s_d = (double*)(ws + 65536);           //   8 KB
  int* idxo = (int*)(ws + 73728);                //  80 KB
  float* xT = (float*)(ws + 155648);             //   4 MB (N x C)
  float* epsT = (float*)(ws + 4349952);          //   4 MB
  float* hT = (float*)(ws + 8544256);            //   4 MB (N x C)
  // union region: partials (16 MB, dead after topk) / Acat+Bcat (18 MB)
  float* partials = (float*)(ws + 12738560);             // 4 x 4 MB
  unsigned short* Acat = (unsigned short*)(ws + 12738560);   // 12 MB
  unsigned short* Bcat = (unsigned short*)(ws + 25321472);   //  6 MB

  norms_partial_kernel<<<dim3(4, 8), 256, 0, stream>>>(x, part);
  norms_reduce_kernel<<<4, 256, 0, stream>>>(part, s_d);

  // dist dot-products: fp32, split-K=4 -> 1024 wg (4 blocks/CU)
  gemm64_split<256><<<dim3(16, 16, 4), 256, 0, stream>>>(
      x, x, partials, N_DIM, N_DIM);

  topk_kernel<<<N_DIM, 64, 0, stream>>>(partials, s_d, idxo);

  transpose_kernel<<<dim3(32, 32), 256, 0, stream>>>(x, xT, C_DIM, N_DIM);
  transpose_kernel<<<dim3(32, 32), 256, 0, stream>>>(eps, epsT, C_DIM, N_DIM);

  gather_kernel<<<N_DIM, 256, 0, stream>>>(xT, epsT, idxo, hT);

  // split-bf16 operand build (after topk: reuses partials region)
  conv_cat_kernel<<<3072, 256, 0, stream>>>(W, Acat, 0);   // hi,hi,lo
  conv_cat_kernel<<<1536, 256, 0, stream>>>(hT, Bcat, 1);  // hi,lo,hi

  // out = W @ h via bf16 MFMA, K'=3072, grid 16x32 = 512 wg
  mfma_gemm<<<dim3(16, 32), 256, 0, stream>>>(Acat, Bcat, out, O_DIM, N_DIM);
}